// Round 8
// baseline (429.092 us; speedup 1.0000x reference)
//
#include <hip/hip_runtime.h>
#include <float.h>

#define D_DIM 768
#define K_DIM 500
#define NIT   12          // 768 / 64 outer steps (2 sub-tiles of 32 each)
#define BM    64          // rows per block
#define NTH   256
#define PB_STRIDE 100352  // padded per-half partial stride (rows)

typedef _Float16 f16x8 __attribute__((ext_vector_type(8)));
typedef float    f32x4 __attribute__((ext_vector_type(4)));

// ws layout:
//   0        : cnorm   float[512]                 (2 KB)
//   4096     : partial double[16*512]             (64 KB)
//   131072   : BpH     _Float16[24*512*32]        (768 KB)
//   917504   : BpL     _Float16[24*512*32]        (768 KB)
//   1703936  : pbv     float[2*PB_STRIDE]         (~800 KB)
//   2506752  : pbi     int[2*PB_STRIDE]           (~800 KB)

// ---------------- cnorm prep (exact, fp64) ----------------
__global__ void cnorm_partial_kernel(const float* __restrict__ C,
                                     double* __restrict__ partial, int K) {
    const int k = threadIdx.x;
    const int w = blockIdx.x;    // 0..15
    double s = 0.0;
    if (k < K) {
        const int d0 = w * (D_DIM / 16);
        for (int d = d0; d < d0 + (D_DIM / 16); ++d) {
            const float c = C[(size_t)d * K + k];
            s = fma((double)c, (double)c, s);
        }
    }
    partial[w * 512 + k] = s;
}

__global__ void cnorm_finish_kernel(const double* __restrict__ partial,
                                    float* __restrict__ cnorm, int K) {
    const int k = threadIdx.x;
    if (k < K) {
        double s = 0.0;
        for (int w = 0; w < 16; ++w) s += partial[w * 512 + k];
        cnorm[k] = (float)s;
    } else {
        cnorm[k] = FLT_MAX;
    }
}

// ---------------- pack C into fragment-ready f16 hi/lo planes ----------------
__global__ void packB_kernel(const float* __restrict__ C,
                             _Float16* __restrict__ BpH,
                             _Float16* __restrict__ BpL) {
    const int idx = blockIdx.x * 256 + threadIdx.x;   // 0..12287
    const int col = idx & 511;
    const int dt  = idx >> 9;                         // 0..23
    f16x8 h[4], l[4];
    #pragma unroll
    for (int c = 0; c < 4; ++c)
        #pragma unroll
        for (int j = 0; j < 8; ++j) {
            const int k = c * 8 + j;
            const float v = (col < K_DIM)
                          ? C[(size_t)(dt * 32 + k) * K_DIM + col] : 0.0f;
            const _Float16 hh = (_Float16)v;
            h[c][j] = hh;
            l[c][j] = (_Float16)(v - (float)hh);
        }
    f16x8* dH = (f16x8*)(BpH + ((size_t)dt * 512 + col) * 32);
    f16x8* dL = (f16x8*)(BpL + ((size_t)dt * 512 + col) * 32);
    #pragma unroll
    for (int c = 0; c < 4; ++c) { dH[c] = h[c]; dL[c] = l[c]; }
}

// ------- main: col-split fp16-split MFMA, 64x256/block, BD=64, partial argmin
__launch_bounds__(NTH, 3)
__global__ void assign_kernel(const float* __restrict__ feat,
                              const _Float16* __restrict__ BpH,
                              const _Float16* __restrict__ BpL,
                              const float* __restrict__ cnorm,
                              float* __restrict__ pbv,
                              int* __restrict__ pbi,
                              int T) {
    // A tiles: [buf][sub][64 rows][32 k] f16, double-buffered: 16 KB per plane
    __shared__ __align__(16) _Float16 AsH[2][2][BM * 32];
    __shared__ __align__(16) _Float16 AsL[2][2][BM * 32];
    __shared__ float red_v[BM * 4];
    __shared__ int   red_i[BM * 4];

    const int tid  = threadIdx.x;
    const int wn   = tid >> 6;    // 0..3 (64-col slice)
    const int lane = tid & 63;
    const int l15  = lane & 15;
    const int kg   = lane >> 4;   // 0..3 (k-group)
    const int bid  = blockIdx.x;
    const int half = bid & 1;     // col half: 0 -> cols 0..255, 1 -> 256..511
    const int R0   = (bid >> 1) * BM;

    // A staging map: 4 threads per row, 8 floats per sub each
    const int ar = tid >> 2;            // 0..63
    const int ac = (tid & 3) << 3;      // 0,8,16,24
    const bool arow_ok = (R0 + ar) < T;
    const float* fptr = feat + (size_t)(R0 + ar) * D_DIM + ac;
    const int asl = ((ac >> 3) + (ar >> 1)) & 3;      // slot swizzle for write

    // B fragment base: global col = half*256 + wn*64 + l15, k-chunk kg
    const int colbase = half * 256 + wn * 64 + l15;
    const _Float16* bpH = BpH + (size_t)colbase * 32 + kg * 8;
    const _Float16* bpL = BpL + (size_t)colbase * 32 + kg * 8;

    f32x4 acc[4][4];
    #pragma unroll
    for (int m = 0; m < 4; ++m)
        #pragma unroll
        for (int n = 0; n < 4; ++n) acc[m][n] = (f32x4){0.f, 0.f, 0.f, 0.f};

#define CVT_STORE(V0, V1, BUF, SUB) do {                                       \
    const float fa[8] = {(V0).x, (V0).y, (V0).z, (V0).w,                       \
                         (V1).x, (V1).y, (V1).z, (V1).w};                      \
    f16x8 h, l;                                                                \
    _Pragma("unroll")                                                          \
    for (int j = 0; j < 8; ++j) {                                              \
        const _Float16 hh = (_Float16)fa[j];                                   \
        h[j] = hh; l[j] = (_Float16)(fa[j] - (float)hh);                       \
    }                                                                          \
    ((f16x8*)AsH[BUF][SUB])[ar * 4 + asl] = h;                                 \
    ((f16x8*)AsL[BUF][SUB])[ar * 4 + asl] = l;                                 \
} while (0)

    // ---- prologue: stage A (both subs) for it = 0
    {
        float4 v0 = make_float4(0.f,0.f,0.f,0.f), v1 = v0, v2 = v0, v3 = v0;
        if (arow_ok) {
            v0 = *(const float4*)(fptr);
            v1 = *(const float4*)(fptr + 4);
            v2 = *(const float4*)(fptr + 32);
            v3 = *(const float4*)(fptr + 36);
        }
        CVT_STORE(v0, v1, 0, 0);
        CVT_STORE(v2, v3, 0, 1);
    }
    __syncthreads();

    for (int it = 0; it < NIT; ++it) {
        const int cur = it & 1;
        const bool hasNext = (it + 1) < NIT;

        // ---- B loads for BOTH sub-tiles issued first (in-order vmcnt:
        //      MFMA sub0 waits <=12 outstanding, sub1 waits <=4, A never drained)
        const size_t bo0 = (size_t)(2 * it) * 16384;
        const size_t bo1 = bo0 + 16384;
        f16x8 b0H[4], b0L[4], b1H[4], b1L[4];
        #pragma unroll
        for (int nh = 0; nh < 4; ++nh) {
            b0H[nh] = *(const f16x8*)(bpH + bo0 + nh * 512);
            b0L[nh] = *(const f16x8*)(bpL + bo0 + nh * 512);
        }
        #pragma unroll
        for (int nh = 0; nh < 4; ++nh) {
            b1H[nh] = *(const f16x8*)(bpH + bo1 + nh * 512);
            b1L[nh] = *(const f16x8*)(bpL + bo1 + nh * 512);
        }

        // ---- next-iteration raw A loads (HBM; retired only at CVT_STORE below)
        float4 v0 = make_float4(0.f,0.f,0.f,0.f), v1 = v0, v2 = v0, v3 = v0;
        if (hasNext && arow_ok) {
            const float* p = fptr + (it + 1) * 64;
            v0 = *(const float4*)(p);
            v1 = *(const float4*)(p + 4);
            v2 = *(const float4*)(p + 32);
            v3 = *(const float4*)(p + 36);
        }

        // ---- sub0: A frags + MFMA
        {
            f16x8 aH[4], aL[4];
            #pragma unroll
            for (int m = 0; m < 4; ++m) {
                const int row = m * 16 + l15;
                const int sl  = (kg + (row >> 1)) & 3;
                aH[m] = ((const f16x8*)AsH[cur][0])[row * 4 + sl];
                aL[m] = ((const f16x8*)AsL[cur][0])[row * 4 + sl];
            }
            __builtin_amdgcn_s_setprio(1);
            #pragma unroll
            for (int nh = 0; nh < 4; ++nh)
                #pragma unroll
                for (int m = 0; m < 4; ++m) {
                    f32x4 a = acc[m][nh];
                    a = __builtin_amdgcn_mfma_f32_16x16x32_f16(aH[m], b0H[nh], a, 0, 0, 0);
                    a = __builtin_amdgcn_mfma_f32_16x16x32_f16(aL[m], b0H[nh], a, 0, 0, 0);
                    a = __builtin_amdgcn_mfma_f32_16x16x32_f16(aH[m], b0L[nh], a, 0, 0, 0);
                    acc[m][nh] = a;
                }
            __builtin_amdgcn_s_setprio(0);
        }

        // ---- sub1: A frags + MFMA
        {
            f16x8 aH[4], aL[4];
            #pragma unroll
            for (int m = 0; m < 4; ++m) {
                const int row = m * 16 + l15;
                const int sl  = (kg + (row >> 1)) & 3;
                aH[m] = ((const f16x8*)AsH[cur][1])[row * 4 + sl];
                aL[m] = ((const f16x8*)AsL[cur][1])[row * 4 + sl];
            }
            __builtin_amdgcn_s_setprio(1);
            #pragma unroll
            for (int nh = 0; nh < 4; ++nh)
                #pragma unroll
                for (int m = 0; m < 4; ++m) {
                    f32x4 a = acc[m][nh];
                    a = __builtin_amdgcn_mfma_f32_16x16x32_f16(aH[m], b1H[nh], a, 0, 0, 0);
                    a = __builtin_amdgcn_mfma_f32_16x16x32_f16(aL[m], b1H[nh], a, 0, 0, 0);
                    a = __builtin_amdgcn_mfma_f32_16x16x32_f16(aH[m], b1L[nh], a, 0, 0, 0);
                    acc[m][nh] = a;
                }
            __builtin_amdgcn_s_setprio(0);
        }

        // ---- convert + stage next A tile into buf[cur^1]
        if (hasNext) {
            CVT_STORE(v0, v1, cur ^ 1, 0);
            CVT_STORE(v2, v3, cur ^ 1, 1);
        }
        __syncthreads();
    }
#undef CVT_STORE

    // ---------------- epilogue: partial argmin over this block's 256 cols ----
    float cn[4];
    #pragma unroll
    for (int nh = 0; nh < 4; ++nh)
        cn[nh] = cnorm[half * 256 + wn * 64 + nh * 16 + l15];

    #pragma unroll
    for (int m = 0; m < 4; ++m) {
        #pragma unroll
        for (int r = 0; r < 4; ++r) {
            float best = cn[0] - 2.0f * acc[m][0][r];
            int   bi   = colbase;
            #pragma unroll
            for (int nh = 1; nh < 4; ++nh) {
                const int col = colbase + nh * 16;
                const float s = cn[nh] - 2.0f * acc[m][nh][r];
                if (s < best || (s == best && col < bi)) { best = s; bi = col; }
            }
            #pragma unroll
            for (int msk = 1; msk < 16; msk <<= 1) {
                const float ov = __shfl_xor(best, msk, 64);
                const int   oi = __shfl_xor(bi,   msk, 64);
                if (ov < best || (ov == best && oi < bi)) { best = ov; bi = oi; }
            }
            if (l15 == 0) {
                const int rl = m * 16 + kg * 4 + r;
                red_v[rl * 4 + wn] = best;
                red_i[rl * 4 + wn] = bi;
            }
        }
    }
    __syncthreads();

    if (tid < BM) {
        float bv = red_v[tid * 4];
        int   bi = red_i[tid * 4];
        #pragma unroll
        for (int w = 1; w < 4; ++w) {
            const float v = red_v[tid * 4 + w];
            const int   i = red_i[tid * 4 + w];
            if (v < bv || (v == bv && i < bi)) { bv = v; bi = i; }
        }
        const int r = R0 + tid;
        if (r < T) {
            pbv[(size_t)half * PB_STRIDE + r] = bv;
            pbi[(size_t)half * PB_STRIDE + r] = bi;
        }
    }
}

// ---------------- combine the two col-half partials ----------------
__global__ void combine_kernel(const float* __restrict__ pbv,
                               const int* __restrict__ pbi,
                               int* __restrict__ out, int T) {
    const int r = blockIdx.x * 256 + threadIdx.x;
    if (r < T) {
        const float s0 = pbv[r];
        const int   i0 = pbi[r];
        const float s1 = pbv[PB_STRIDE + r];
        const int   i1 = pbi[PB_STRIDE + r];
        // exact tie -> half 0 (lower index), matching numpy argmin
        out[r] = (s1 < s0) ? i1 : i0;
    }
}

extern "C" void kernel_launch(void* const* d_in, const int* in_sizes, int n_in,
                              void* d_out, int out_size, void* d_ws, size_t ws_size,
                              hipStream_t stream) {
    const float* feat = (const float*)d_in[0];
    const float* C    = (const float*)d_in[1];
    int* out          = (int*)d_out;
    const int T = in_sizes[0] / D_DIM;   // 100000
    const int K = in_sizes[1] / D_DIM;   // 500

    float*     cnorm   = (float*)d_ws;
    double*    partial = (double*)((char*)d_ws + 4096);
    _Float16*  BpH     = (_Float16*)((char*)d_ws + 131072);
    _Float16*  BpL     = (_Float16*)((char*)d_ws + 917504);
    float*     pbv     = (float*)((char*)d_ws + 1703936);
    int*       pbi     = (int*)((char*)d_ws + 2506752);

    hipLaunchKernelGGL(cnorm_partial_kernel, dim3(16), dim3(512), 0, stream,
                       C, partial, K);
    hipLaunchKernelGGL(cnorm_finish_kernel, dim3(1), dim3(512), 0, stream,
                       partial, cnorm, K);
    hipLaunchKernelGGL(packB_kernel, dim3(48), dim3(256), 0, stream,
                       C, BpH, BpL);

    const int nrb = (T + BM - 1) / BM;            // row blocks
    hipLaunchKernelGGL(assign_kernel, dim3(nrb * 2), dim3(NTH), 0, stream,
                       feat, BpH, BpL, cnorm, pbv, pbi, T);
    hipLaunchKernelGGL(combine_kernel, dim3((T + 255) / 256), dim3(256), 0, stream,
                       pbv, pbi, out, T);
}

// Round 9
// 265.931 us; speedup vs baseline: 1.6135x; 1.6135x over previous
//
#include <hip/hip_runtime.h>
#include <float.h>

#define D_DIM 768
#define K_DIM 500
#define NDT   24          // 768 / 32 D-tiles
#define BM    64          // rows per block
#define NTH   256
#define PB_STRIDE 100352  // padded per-half partial stride (rows)

typedef _Float16 f16x8 __attribute__((ext_vector_type(8)));
typedef float    f32x4 __attribute__((ext_vector_type(4)));

// ws layout:
//   0        : cnorm   float[512]                 (2 KB)
//   4096     : partial double[16*512]             (64 KB)
//   131072   : BpH     _Float16[24*512*32]        (768 KB)
//   917504   : BpL     _Float16[24*512*32]        (768 KB)
//   1703936  : pbv     float[2*PB_STRIDE]         (~800 KB)
//   2506752  : pbi     int[2*PB_STRIDE]           (~800 KB)

// ---------------- cnorm prep (exact, fp64) ----------------
__global__ void cnorm_partial_kernel(const float* __restrict__ C,
                                     double* __restrict__ partial, int K) {
    const int k = threadIdx.x;
    const int w = blockIdx.x;    // 0..15
    double s = 0.0;
    if (k < K) {
        const int d0 = w * (D_DIM / 16);
        for (int d = d0; d < d0 + (D_DIM / 16); ++d) {
            const float c = C[(size_t)d * K + k];
            s = fma((double)c, (double)c, s);
        }
    }
    partial[w * 512 + k] = s;
}

__global__ void cnorm_finish_kernel(const double* __restrict__ partial,
                                    float* __restrict__ cnorm, int K) {
    const int k = threadIdx.x;
    if (k < K) {
        double s = 0.0;
        for (int w = 0; w < 16; ++w) s += partial[w * 512 + k];
        cnorm[k] = (float)s;
    } else {
        cnorm[k] = FLT_MAX;
    }
}

// ---------------- pack C into fragment-ready f16 hi/lo planes ----------------
__global__ void packB_kernel(const float* __restrict__ C,
                             _Float16* __restrict__ BpH,
                             _Float16* __restrict__ BpL) {
    const int idx = blockIdx.x * 256 + threadIdx.x;   // 0..12287
    const int col = idx & 511;
    const int dt  = idx >> 9;                         // 0..23
    f16x8 h[4], l[4];
    #pragma unroll
    for (int c = 0; c < 4; ++c)
        #pragma unroll
        for (int j = 0; j < 8; ++j) {
            const int k = c * 8 + j;
            const float v = (col < K_DIM)
                          ? C[(size_t)(dt * 32 + k) * K_DIM + col] : 0.0f;
            const _Float16 hh = (_Float16)v;
            h[c][j] = hh;
            l[c][j] = (_Float16)(v - (float)hh);
        }
    f16x8* dH = (f16x8*)(BpH + ((size_t)dt * 512 + col) * 32);
    f16x8* dL = (f16x8*)(BpL + ((size_t)dt * 512 + col) * 32);
    #pragma unroll
    for (int c = 0; c < 4; ++c) { dH[c] = h[c]; dL[c] = l[c]; }
}

// ------- main: col-split fp16-split MFMA, 64x256/block, A prefetch depth-2 ---
__launch_bounds__(NTH, 3)
__global__ void assign_kernel(const float* __restrict__ feat,
                              const _Float16* __restrict__ BpH,
                              const _Float16* __restrict__ BpL,
                              const float* __restrict__ cnorm,
                              float* __restrict__ pbv,
                              int* __restrict__ pbi,
                              int T) {
    // A tiles double-buffered: 2 planes x 2 bufs x 4KB = 16KB
    __shared__ __align__(16) _Float16 AsH[2][BM * 32];
    __shared__ __align__(16) _Float16 AsL[2][BM * 32];
    __shared__ float red_v[BM * 4];
    __shared__ int   red_i[BM * 4];

    const int tid  = threadIdx.x;
    const int wn   = tid >> 6;    // 0..3 (64-col slice)
    const int lane = tid & 63;
    const int l15  = lane & 15;
    const int kg   = lane >> 4;   // 0..3 (k-group)
    const int bid  = blockIdx.x;
    const int half = bid & 1;     // col half: 0 -> cols 0..255, 1 -> 256..511
    const int R0   = (bid >> 1) * BM;

    // A staging map: 4 threads per row, 8 floats each
    const int ar = tid >> 2;            // 0..63
    const int ac = (tid & 3) << 3;      // 0,8,16,24
    const bool arow_ok = (R0 + ar) < T;
    const float* fptr = feat + (size_t)(R0 + ar) * D_DIM + ac;
    const int asl = ((ac >> 3) + (ar >> 1)) & 3;      // slot swizzle for write

    // B fragment base: global col = half*256 + wn*64 + l15, k-chunk kg
    const int colbase = half * 256 + wn * 64 + l15;
    const _Float16* bpH = BpH + (size_t)colbase * 32 + kg * 8;
    const _Float16* bpL = BpL + (size_t)colbase * 32 + kg * 8;

    f32x4 acc[4][4];
    #pragma unroll
    for (int m = 0; m < 4; ++m)
        #pragma unroll
        for (int n = 0; n < 4; ++n) acc[m][n] = (f32x4){0.f, 0.f, 0.f, 0.f};

#define CVT_STORE(V0, V1, BUF) do {                                            \
    const float fa[8] = {(V0).x, (V0).y, (V0).z, (V0).w,                       \
                         (V1).x, (V1).y, (V1).z, (V1).w};                      \
    f16x8 h, l;                                                                \
    _Pragma("unroll")                                                          \
    for (int j = 0; j < 8; ++j) {                                              \
        const _Float16 hh = (_Float16)fa[j];                                   \
        h[j] = hh; l[j] = (_Float16)(fa[j] - (float)hh);                       \
    }                                                                          \
    ((f16x8*)AsH[BUF])[ar * 4 + asl] = h;                                      \
    ((f16x8*)AsL[BUF])[ar * 4 + asl] = l;                                      \
} while (0)

// One dt iteration. CUR0/CUR1 hold raw A for dt+1 (consumed by CVT here);
// NXT0/NXT1 receive raw A for dt+2 (consumed next iteration).
#define BODY(DT, CUR0, CUR1, NXT0, NXT1) do {                                  \
    const int cur = (DT) & 1;                                                  \
    /* B fragments for this dt (issued first; MFMA's vmcnt wait leaves the */  \
    /* later-issued A prefetch in flight) */                                   \
    const size_t bo = (size_t)(DT) * 16384;                                    \
    f16x8 bH[4], bL[4];                                                        \
    _Pragma("unroll")                                                          \
    for (int nh = 0; nh < 4; ++nh) {                                           \
        bH[nh] = *(const f16x8*)(bpH + bo + nh * 512);                         \
        bL[nh] = *(const f16x8*)(bpL + bo + nh * 512);                         \
    }                                                                          \
    /* raw A prefetch for dt+2 (full iteration of slack before use) */         \
    if ((DT) + 2 < NDT && arow_ok) {                                           \
        const float* p = fptr + ((DT) + 2) * 32;                               \
        NXT0 = *(const float4*)(p);                                            \
        NXT1 = *(const float4*)(p + 4);                                        \
    }                                                                          \
    /* A fragments from LDS buf[cur] */                                        \
    f16x8 aH[4], aL[4];                                                        \
    _Pragma("unroll")                                                          \
    for (int m = 0; m < 4; ++m) {                                              \
        const int row = m * 16 + l15;                                          \
        const int sl  = (kg + (row >> 1)) & 3;                                 \
        aH[m] = ((const f16x8*)AsH[cur])[row * 4 + sl];                        \
        aL[m] = ((const f16x8*)AsL[cur])[row * 4 + sl];                        \
    }                                                                          \
    __builtin_amdgcn_s_setprio(1);                                             \
    _Pragma("unroll")                                                          \
    for (int nh = 0; nh < 4; ++nh)                                             \
        _Pragma("unroll")                                                      \
        for (int m = 0; m < 4; ++m) {                                          \
            f32x4 a = acc[m][nh];                                              \
            a = __builtin_amdgcn_mfma_f32_16x16x32_f16(aH[m], bH[nh], a, 0, 0, 0); \
            a = __builtin_amdgcn_mfma_f32_16x16x32_f16(aL[m], bH[nh], a, 0, 0, 0); \
            a = __builtin_amdgcn_mfma_f32_16x16x32_f16(aH[m], bL[nh], a, 0, 0, 0); \
            acc[m][nh] = a;                                                    \
        }                                                                      \
    __builtin_amdgcn_s_setprio(0);                                             \
    /* stage dt+1 tile from CUR regs (loaded a full iteration ago) */          \
    if ((DT) + 1 < NDT) {                                                      \
        CVT_STORE(CUR0, CUR1, cur ^ 1);                                        \
    }                                                                          \
    __syncthreads();                                                           \
} while (0)

    // ---- prologue: stage dt=0 synchronously; prefetch raw A for dt=1
    {
        float4 v0 = make_float4(0.f, 0.f, 0.f, 0.f), v1 = v0;
        if (arow_ok) {
            v0 = *(const float4*)(fptr);
            v1 = *(const float4*)(fptr + 4);
        }
        CVT_STORE(v0, v1, 0);
    }
    float4 pa0 = make_float4(0.f, 0.f, 0.f, 0.f), pa1 = pa0;
    float4 pb0 = pa0, pb1 = pa0;
    if (arow_ok) {
        pa0 = *(const float4*)(fptr + 32);
        pa1 = *(const float4*)(fptr + 36);
    }
    __syncthreads();

    // ---- main loop, unrolled by 2 so the prefetch reg sets have static names
    for (int it2 = 0; it2 < NDT; it2 += 2) {
        BODY(it2,     pa0, pa1, pb0, pb1);
        BODY(it2 + 1, pb0, pb1, pa0, pa1);
    }
#undef BODY
#undef CVT_STORE

    // ---------------- epilogue: partial argmin over this block's 256 cols ----
    float cn[4];
    #pragma unroll
    for (int nh = 0; nh < 4; ++nh)
        cn[nh] = cnorm[half * 256 + wn * 64 + nh * 16 + l15];

    #pragma unroll
    for (int m = 0; m < 4; ++m) {
        #pragma unroll
        for (int r = 0; r < 4; ++r) {
            float best = cn[0] - 2.0f * acc[m][0][r];
            int   bi   = colbase;
            #pragma unroll
            for (int nh = 1; nh < 4; ++nh) {
                const int col = colbase + nh * 16;
                const float s = cn[nh] - 2.0f * acc[m][nh][r];
                if (s < best || (s == best && col < bi)) { best = s; bi = col; }
            }
            #pragma unroll
            for (int msk = 1; msk < 16; msk <<= 1) {
                const float ov = __shfl_xor(best, msk, 64);
                const int   oi = __shfl_xor(bi,   msk, 64);
                if (ov < best || (ov == best && oi < bi)) { best = ov; bi = oi; }
            }
            if (l15 == 0) {
                const int rl = m * 16 + kg * 4 + r;
                red_v[rl * 4 + wn] = best;
                red_i[rl * 4 + wn] = bi;
            }
        }
    }
    __syncthreads();

    if (tid < BM) {
        float bv = red_v[tid * 4];
        int   bi = red_i[tid * 4];
        #pragma unroll
        for (int w = 1; w < 4; ++w) {
            const float v = red_v[tid * 4 + w];
            const int   i = red_i[tid * 4 + w];
            if (v < bv || (v == bv && i < bi)) { bv = v; bi = i; }
        }
        const int r = R0 + tid;
        if (r < T) {
            pbv[(size_t)half * PB_STRIDE + r] = bv;
            pbi[(size_t)half * PB_STRIDE + r] = bi;
        }
    }
}

// ---------------- combine the two col-half partials ----------------
__global__ void combine_kernel(const float* __restrict__ pbv,
                               const int* __restrict__ pbi,
                               int* __restrict__ out, int T) {
    const int r = blockIdx.x * 256 + threadIdx.x;
    if (r < T) {
        const float s0 = pbv[r];
        const int   i0 = pbi[r];
        const float s1 = pbv[PB_STRIDE + r];
        const int   i1 = pbi[PB_STRIDE + r];
        // exact tie -> half 0 (lower index), matching numpy argmin
        out[r] = (s1 < s0) ? i1 : i0;
    }
}

extern "C" void kernel_launch(void* const* d_in, const int* in_sizes, int n_in,
                              void* d_out, int out_size, void* d_ws, size_t ws_size,
                              hipStream_t stream) {
    const float* feat = (const float*)d_in[0];
    const float* C    = (const float*)d_in[1];
    int* out          = (int*)d_out;
    const int T = in_sizes[0] / D_DIM;   // 100000
    const int K = in_sizes[1] / D_DIM;   // 500

    float*     cnorm   = (float*)d_ws;
    double*    partial = (double*)((char*)d_ws + 4096);
    _Float16*  BpH     = (_Float16*)((char*)d_ws + 131072);
    _Float16*  BpL     = (_Float16*)((char*)d_ws + 917504);
    float*     pbv     = (float*)((char*)d_ws + 1703936);
    int*       pbi     = (int*)((char*)d_ws + 2506752);

    hipLaunchKernelGGL(cnorm_partial_kernel, dim3(16), dim3(512), 0, stream,
                       C, partial, K);
    hipLaunchKernelGGL(cnorm_finish_kernel, dim3(1), dim3(512), 0, stream,
                       partial, cnorm, K);
    hipLaunchKernelGGL(packB_kernel, dim3(48), dim3(256), 0, stream,
                       C, BpH, BpL);

    const int nrb = (T + BM - 1) / BM;            // row blocks
    hipLaunchKernelGGL(assign_kernel, dim3(nrb * 2), dim3(NTH), 0, stream,
                       feat, BpH, BpL, cnorm, pbv, pbi, T);
    hipLaunchKernelGGL(combine_kernel, dim3((T + 255) / 256), dim3(256), 0, stream,
                       pbv, pbi, out, T);
}

// Round 10
// 265.925 us; speedup vs baseline: 1.6136x; 1.0000x over previous
//
#include <hip/hip_runtime.h>
#include <float.h>

#define D_DIM 768
#define K_DIM 500
#define NDT   24          // 768 / 32 D-tiles
#define BM    64          // rows per block
#define NTH   256
#define PB_STRIDE 100352  // padded per-half partial stride (rows)

typedef _Float16 f16x8 __attribute__((ext_vector_type(8)));
typedef float    f32x4 __attribute__((ext_vector_type(4)));

// ws layout:
//   0        : cnorm   float[512]                 (2 KB)
//   4096     : partial double[16*512]             (64 KB)
//   131072   : BpH     _Float16[24*512*32]        (768 KB)
//   917504   : BpL     _Float16[24*512*32]        (768 KB)
//   1703936  : pbv     float[2*PB_STRIDE]         (~800 KB)
//   2506752  : pbi     int[2*PB_STRIDE]           (~800 KB)

// ---------------- cnorm prep (exact, fp64) ----------------
__global__ void cnorm_partial_kernel(const float* __restrict__ C,
                                     double* __restrict__ partial, int K) {
    const int k = threadIdx.x;
    const int w = blockIdx.x;    // 0..15
    double s = 0.0;
    if (k < K) {
        const int d0 = w * (D_DIM / 16);
        for (int d = d0; d < d0 + (D_DIM / 16); ++d) {
            const float c = C[(size_t)d * K + k];
            s = fma((double)c, (double)c, s);
        }
    }
    partial[w * 512 + k] = s;
}

__global__ void cnorm_finish_kernel(const double* __restrict__ partial,
                                    float* __restrict__ cnorm, int K) {
    const int k = threadIdx.x;
    if (k < K) {
        double s = 0.0;
        for (int w = 0; w < 16; ++w) s += partial[w * 512 + k];
        cnorm[k] = (float)s;
    } else {
        cnorm[k] = FLT_MAX;
    }
}

// ---------------- pack C into fragment-ready f16 hi/lo planes ----------------
__global__ void packB_kernel(const float* __restrict__ C,
                             _Float16* __restrict__ BpH,
                             _Float16* __restrict__ BpL) {
    const int idx = blockIdx.x * 256 + threadIdx.x;   // 0..12287
    const int col = idx & 511;
    const int dt  = idx >> 9;                         // 0..23
    f16x8 h[4], l[4];
    #pragma unroll
    for (int c = 0; c < 4; ++c)
        #pragma unroll
        for (int j = 0; j < 8; ++j) {
            const int k = c * 8 + j;
            const float v = (col < K_DIM)
                          ? C[(size_t)(dt * 32 + k) * K_DIM + col] : 0.0f;
            const _Float16 hh = (_Float16)v;
            h[c][j] = hh;
            l[c][j] = (_Float16)(v - (float)hh);
        }
    f16x8* dH = (f16x8*)(BpH + ((size_t)dt * 512 + col) * 32);
    f16x8* dL = (f16x8*)(BpL + ((size_t)dt * 512 + col) * 32);
    #pragma unroll
    for (int c = 0; c < 4; ++c) { dH[c] = h[c]; dL[c] = l[c]; }
}

// ------- main: col-split fp16-split MFMA, counted-vmcnt barrier pipeline -----
__launch_bounds__(NTH, 3)
__global__ void assign_kernel(const float* __restrict__ feat,
                              const _Float16* __restrict__ BpH,
                              const _Float16* __restrict__ BpL,
                              const float* __restrict__ cnorm,
                              float* __restrict__ pbv,
                              int* __restrict__ pbi,
                              int T) {
    // A tiles double-buffered: 2 planes x 2 bufs x 4KB = 16KB
    __shared__ __align__(16) _Float16 AsH[2][BM * 32];
    __shared__ __align__(16) _Float16 AsL[2][BM * 32];
    __shared__ float red_v[BM * 4];
    __shared__ int   red_i[BM * 4];

    const int tid  = threadIdx.x;
    const int wn   = tid >> 6;    // 0..3 (64-col slice)
    const int lane = tid & 63;
    const int l15  = lane & 15;
    const int kg   = lane >> 4;   // 0..3 (k-group)
    const int bid  = blockIdx.x;
    const int half = bid & 1;     // col half: 0 -> cols 0..255, 1 -> 256..511
    const int R0   = (bid >> 1) * BM;

    // A staging map: 4 threads per row, 8 floats each
    const int ar = tid >> 2;            // 0..63
    const int ac = (tid & 3) << 3;      // 0,8,16,24
    const bool arow_ok = (R0 + ar) < T;
    const float* fptr = feat + (size_t)(R0 + ar) * D_DIM + ac;
    const int asl = ((ac >> 3) + (ar >> 1)) & 3;      // slot swizzle for write

    // B fragment base: global col = half*256 + wn*64 + l15, k-chunk kg
    const int colbase = half * 256 + wn * 64 + l15;
    const _Float16* bpH = BpH + (size_t)colbase * 32 + kg * 8;
    const _Float16* bpL = BpL + (size_t)colbase * 32 + kg * 8;

    f32x4 acc[4][4];
    #pragma unroll
    for (int m = 0; m < 4; ++m)
        #pragma unroll
        for (int n = 0; n < 4; ++n) acc[m][n] = (f32x4){0.f, 0.f, 0.f, 0.f};

#define CVT_STORE(V0, V1, BUF) do {                                            \
    const float fa[8] = {(V0).x, (V0).y, (V0).z, (V0).w,                       \
                         (V1).x, (V1).y, (V1).z, (V1).w};                      \
    f16x8 h, l;                                                                \
    _Pragma("unroll")                                                          \
    for (int j = 0; j < 8; ++j) {                                              \
        const _Float16 hh = (_Float16)fa[j];                                   \
        h[j] = hh; l[j] = (_Float16)(fa[j] - (float)hh);                       \
    }                                                                          \
    ((f16x8*)AsH[BUF])[ar * 4 + asl] = h;                                      \
    ((f16x8*)AsL[BUF])[ar * 4 + asl] = l;                                      \
} while (0)

// Counted barrier: ds_writes/reads must retire (lgkmcnt 0), but vmcnt is NOT
// drained -> the in-flight A prefetch survives across the barrier and retires
// under the NEXT iteration's B-load wait (it is older than those B loads).
#define SOFT_BARRIER() do {                                                    \
    asm volatile("s_waitcnt lgkmcnt(0)" ::: "memory");                         \
    __builtin_amdgcn_s_barrier();                                              \
} while (0)

// One dt iteration. CUR0/CUR1 hold raw A for dt+1 (consumed by CVT here);
// NXT0/NXT1 receive raw A for dt+2 (consumed next iteration).
#define BODY(DT, CUR0, CUR1, NXT0, NXT1) do {                                  \
    const int cur = (DT) & 1;                                                  \
    /* B fragments for this dt (issued first; MFMA's counted vmcnt wait */     \
    /* retires B and the OLDER A pair, leaving the new A pair in flight) */    \
    const size_t bo = (size_t)(DT) * 16384;                                    \
    f16x8 bH[4], bL[4];                                                        \
    _Pragma("unroll")                                                          \
    for (int nh = 0; nh < 4; ++nh) {                                           \
        bH[nh] = *(const f16x8*)(bpH + bo + nh * 512);                         \
        bL[nh] = *(const f16x8*)(bpL + bo + nh * 512);                         \
    }                                                                          \
    /* raw A prefetch for dt+2 (crosses the soft barrier in registers) */      \
    if ((DT) + 2 < NDT && arow_ok) {                                           \
        const float* p = fptr + ((DT) + 2) * 32;                               \
        NXT0 = *(const float4*)(p);                                            \
        NXT1 = *(const float4*)(p + 4);                                        \
    }                                                                          \
    /* A fragments from LDS buf[cur] */                                        \
    f16x8 aH[4], aL[4];                                                        \
    _Pragma("unroll")                                                          \
    for (int m = 0; m < 4; ++m) {                                              \
        const int row = m * 16 + l15;                                          \
        const int sl  = (kg + (row >> 1)) & 3;                                 \
        aH[m] = ((const f16x8*)AsH[cur])[row * 4 + sl];                        \
        aL[m] = ((const f16x8*)AsL[cur])[row * 4 + sl];                        \
    }                                                                          \
    __builtin_amdgcn_s_setprio(1);                                             \
    _Pragma("unroll")                                                          \
    for (int nh = 0; nh < 4; ++nh)                                             \
        _Pragma("unroll")                                                      \
        for (int m = 0; m < 4; ++m) {                                          \
            f32x4 a = acc[m][nh];                                              \
            a = __builtin_amdgcn_mfma_f32_16x16x32_f16(aH[m], bH[nh], a, 0, 0, 0); \
            a = __builtin_amdgcn_mfma_f32_16x16x32_f16(aL[m], bH[nh], a, 0, 0, 0); \
            a = __builtin_amdgcn_mfma_f32_16x16x32_f16(aH[m], bL[nh], a, 0, 0, 0); \
            acc[m][nh] = a;                                                    \
        }                                                                      \
    __builtin_amdgcn_s_setprio(0);                                             \
    /* stage dt+1 tile from CUR regs (retired by this iter's B vmcnt wait) */  \
    if ((DT) + 1 < NDT) {                                                      \
        CVT_STORE(CUR0, CUR1, cur ^ 1);                                        \
    }                                                                          \
    SOFT_BARRIER();                                                            \
} while (0)

    // ---- prologue: stage dt=0 synchronously; prefetch raw A for dt=1
    {
        float4 v0 = make_float4(0.f, 0.f, 0.f, 0.f), v1 = v0;
        if (arow_ok) {
            v0 = *(const float4*)(fptr);
            v1 = *(const float4*)(fptr + 4);
        }
        CVT_STORE(v0, v1, 0);
    }
    float4 pa0 = make_float4(0.f, 0.f, 0.f, 0.f), pa1 = pa0;
    float4 pb0 = pa0, pb1 = pa0;
    if (arow_ok) {
        pa0 = *(const float4*)(fptr + 32);
        pa1 = *(const float4*)(fptr + 36);
    }
    __syncthreads();

    // ---- main loop, unrolled by 2 so the prefetch reg sets have static names
    for (int it2 = 0; it2 < NDT; it2 += 2) {
        BODY(it2,     pa0, pa1, pb0, pb1);
        BODY(it2 + 1, pb0, pb1, pa0, pa1);
    }
#undef BODY
#undef SOFT_BARRIER
#undef CVT_STORE

    // ---------------- epilogue: partial argmin over this block's 256 cols ----
    float cn[4];
    #pragma unroll
    for (int nh = 0; nh < 4; ++nh)
        cn[nh] = cnorm[half * 256 + wn * 64 + nh * 16 + l15];

    #pragma unroll
    for (int m = 0; m < 4; ++m) {
        #pragma unroll
        for (int r = 0; r < 4; ++r) {
            float best = cn[0] - 2.0f * acc[m][0][r];
            int   bi   = colbase;
            #pragma unroll
            for (int nh = 1; nh < 4; ++nh) {
                const int col = colbase + nh * 16;
                const float s = cn[nh] - 2.0f * acc[m][nh][r];
                if (s < best || (s == best && col < bi)) { best = s; bi = col; }
            }
            #pragma unroll
            for (int msk = 1; msk < 16; msk <<= 1) {
                const float ov = __shfl_xor(best, msk, 64);
                const int   oi = __shfl_xor(bi,   msk, 64);
                if (ov < best || (ov == best && oi < bi)) { best = ov; bi = oi; }
            }
            if (l15 == 0) {
                const int rl = m * 16 + kg * 4 + r;
                red_v[rl * 4 + wn] = best;
                red_i[rl * 4 + wn] = bi;
            }
        }
    }
    __syncthreads();

    if (tid < BM) {
        float bv = red_v[tid * 4];
        int   bi = red_i[tid * 4];
        #pragma unroll
        for (int w = 1; w < 4; ++w) {
            const float v = red_v[tid * 4 + w];
            const int   i = red_i[tid * 4 + w];
            if (v < bv || (v == bv && i < bi)) { bv = v; bi = i; }
        }
        const int r = R0 + tid;
        if (r < T) {
            pbv[(size_t)half * PB_STRIDE + r] = bv;
            pbi[(size_t)half * PB_STRIDE + r] = bi;
        }
    }
}

// ---------------- combine the two col-half partials ----------------
__global__ void combine_kernel(const float* __restrict__ pbv,
                               const int* __restrict__ pbi,
                               int* __restrict__ out, int T) {
    const int r = blockIdx.x * 256 + threadIdx.x;
    if (r < T) {
        const float s0 = pbv[r];
        const int   i0 = pbi[r];
        const float s1 = pbv[PB_STRIDE + r];
        const int   i1 = pbi[PB_STRIDE + r];
        // exact tie -> half 0 (lower index), matching numpy argmin
        out[r] = (s1 < s0) ? i1 : i0;
    }
}

extern "C" void kernel_launch(void* const* d_in, const int* in_sizes, int n_in,
                              void* d_out, int out_size, void* d_ws, size_t ws_size,
                              hipStream_t stream) {
    const float* feat = (const float*)d_in[0];
    const float* C    = (const float*)d_in[1];
    int* out          = (int*)d_out;
    const int T = in_sizes[0] / D_DIM;   // 100000
    const int K = in_sizes[1] / D_DIM;   // 500

    float*     cnorm   = (float*)d_ws;
    double*    partial = (double*)((char*)d_ws + 4096);
    _Float16*  BpH     = (_Float16*)((char*)d_ws + 131072);
    _Float16*  BpL     = (_Float16*)((char*)d_ws + 917504);
    float*     pbv     = (float*)((char*)d_ws + 1703936);
    int*       pbi     = (int*)((char*)d_ws + 2506752);

    hipLaunchKernelGGL(cnorm_partial_kernel, dim3(16), dim3(512), 0, stream,
                       C, partial, K);
    hipLaunchKernelGGL(cnorm_finish_kernel, dim3(1), dim3(512), 0, stream,
                       partial, cnorm, K);
    hipLaunchKernelGGL(packB_kernel, dim3(48), dim3(256), 0, stream,
                       C, BpH, BpL);

    const int nrb = (T + BM - 1) / BM;            // row blocks
    hipLaunchKernelGGL(assign_kernel, dim3(nrb * 2), dim3(NTH), 0, stream,
                       feat, BpH, BpL, cnorm, pbv, pbi, T);
    hipLaunchKernelGGL(combine_kernel, dim3((T + 255) / 256), dim3(256), 0, stream,
                       pbv, pbi, out, T);
}